// Round 5
// baseline (99.589 us; speedup 1.0000x reference)
//
#include <hip/hip_runtime.h>

// Problem constants (from reference: B=8, N=8192, M=2500, P=10)
#define B_   8
#define N_   8192
#define M_   2500
#define SPP_ 250
#define EPS_ 1e-20f
#define BIGF 1e30f

// ---- kernel-1 roles ----
// unified chamfer: 16 gtblk (512 gt) x 8 b x 5 mblk (512 preds) = 640 blocks.
// Each block computes its 512x512 distance tile ONCE. Row minima (p2gt):
// per-block owned slice [z][b][2500]. Col minima (gt2p): per-WAVE owned
// slice [m][w][b][8192], stored in-loop (no scol LDS -> occupancy up).
#define NB_CH   640
#define NB_FFF  79
#define NB_K1   (NB_CH + NB_FFF)   // 719

// ---- kernel-2: min-combine partials + finalize ----
#define NB_SG   64                 // 65536 gt2p outputs (min over 20)
#define NB_SP   20                 // 20000 p2gt outputs (min over 16)
#define NB_K2   (NB_SG + NB_SP)    // 84

// ---- ws layout (float indices); everything plain-stored before read ----
#define WS_P2P  0                  // [16 z][8 b][2500] row-min partials
#define WS_G2P  320000             // [5 m][4 w][8 b][8192] col-min partials
#define WS_SLOT 1630720            // [79][18] fff per-block partials
#define WS_RED  1632142            // [84] k2 per-block partial sums
#define WS_CNT  1632226            // k2 arrival counter (zeroed by k1 blk 0)
// slot indices
#define A_E    0
#define A_G    1
#define A_MC   2
#define A_ST   3
#define A_F2I  4
#define A_E2I  5
#define A_EI   6
#define A_G2I  7
#define A_GI   8
#define A_I    9
#define A_AB   10   // 10..17 per-batch sum sqrt(A2)

typedef __attribute__((ext_vector_type(8))) short short8_t;
typedef __attribute__((ext_vector_type(4))) float float4_t;

__device__ __forceinline__ unsigned pack_bf2(float lo, float hi) {
    unsigned a = __float_as_uint(lo);
    unsigned b = __float_as_uint(hi);
    a = (a + 0x7FFFu + ((a >> 16) & 1u)) >> 16;
    b = (b + 0x7FFFu + ((b >> 16) & 1u)) & 0xFFFF0000u;
    return a | b;
}
__device__ __forceinline__ short bf16s(float x) {
    unsigned a = __float_as_uint(x);
    return (short)((a + 0x7FFFu + ((a >> 16) & 1u)) >> 16);
}
// 3-input min, single VALU instr (values are never NaN here)
__device__ __forceinline__ float min3f(float a, float b, float c) {
    float r;
    asm("v_min3_f32 %0, %1, %2, %3" : "=v"(r) : "v"(a), "v"(b), "v"(c));
    return r;
}
__device__ __forceinline__ float wave_sum64(float v) {
    #pragma unroll
    for (int o = 32; o > 0; o >>= 1) v += __shfl_down(v, o, 64);
    return v;
}
__device__ __forceinline__ float block_sum256(float v, volatile float* red4) {
    v = wave_sum64(v);
    int wid = threadIdx.x >> 6, lane = threadIdx.x & 63;
    if (lane == 0) red4[wid] = v;
    __syncthreads();
    float r = 0.f;
    if (threadIdx.x == 0) r = red4[0] + red4[1] + red4[2] + red4[3];
    __syncthreads();
    return r;
}
__device__ __forceinline__ void quad_min4(float4_t& c) {
    #pragma unroll
    for (int m = 1; m < 16; m <<= 1) {
        c.x = fminf(c.x, __shfl_xor(c.x, m, 64));
        c.y = fminf(c.y, __shfl_xor(c.y, m, 64));
        c.z = fminf(c.z, __shfl_xor(c.z, m, 64));
        c.w = fminf(c.w, __shfl_xor(c.w, m, 64));
    }
}
__device__ __forceinline__ void min4v(float4_t& c, const float4_t d) {
    c.x = fminf(c.x, d.x); c.y = fminf(c.y, d.y);
    c.z = fminf(c.z, d.z); c.w = fminf(c.w, d.w);
}

// ============================================================================
// Kernel 1: MFMA chamfer (one distance-matrix pass, both directions) + fff.
// LDS ~10.3 KB (no scol) + __launch_bounds__(256,4) -> 4 blocks/CU resident,
// 16 waves/CU, vs previous 44 KB / 3 blocks / observed 9% occupancy.
// Col partials stored per-wave in-loop (fire-and-forget global stores).
// ============================================================================
__global__ void __launch_bounds__(256, 4) k1_main(
        const float* __restrict__ gt, const float* __restrict__ pred,
        const float* __restrict__ fff, float* __restrict__ ws) {
    __shared__ uint4 spts[512];                  // staged gt pts, 16 B each
    __shared__ __align__(16) float saux[516];    // 512 row norms + red4
    const int bid = blockIdx.x;
    const int tid = threadIdx.x;
    const int lane = tid & 63;
    const int w    = tid >> 6;
    const int quad = lane >> 4;
    const int l15  = lane & 15;

    if (bid == 0 && tid == 0)
        ((unsigned*)(ws + WS_CNT))[0] = 0u;      // k2 counter (kernel-boundary ordered)

    if (bid < NB_CH) {
        // ------------------- unified chamfer role -------------------
        const int z = bid / 40;         // gt chunk (512 pts), 16 chunks
        const int rem = bid % 40;
        const int b = rem / 5;
        const int mblk = rem % 5;       // pred chunk (512 rows)
        const float* apts = pred + (size_t)b * M_ * 3;
        const float* bpts = gt + ((size_t)b * N_ + (size_t)z * 512) * 3;
        const int abase = mblk * 512;
        float* dstR = ws + WS_P2P + (size_t)z * 20000 + b * M_;   // owned rows
        // per-WAVE owned col-partial slice: [m][w][b][8192], this block's 512 cols
        float* dstCW = ws + WS_G2P
                     + ((size_t)(mblk * 4 + w) * 8 + b) * 8192 + z * 512;

        // stage gt points (bf16, -2 folded, norm in w; halves duplicated)
        for (int i = tid; i < 512; i += 256) {
            const float* q3 = bpts + i * 3;
            float x = q3[0], y = q3[1], zc = q3[2];
            float n2 = x * x + y * y + zc * zc;
            uint4 q;
            q.x = pack_bf2(-2.f * x, -2.f * y);
            q.y = pack_bf2(-2.f * zc, n2);
            q.z = q.x; q.w = q.y;
            spts[i] = q;
        }

        // A fragments: 8 tiles of 16 rows per wave (128 rows); stash norms
        short8_t af[8];
        #pragma unroll
        for (int t = 0; t < 8; ++t) af[t] = (short8_t){0,0,0,0,0,0,0,0};
        if (lane < 16) {
            #pragma unroll
            for (int t = 0; t < 8; ++t) {
                int m = abase + w * 128 + t * 16 + l15;
                int c = m < M_ ? m : M_ - 1;   // dup row 2499 (harmless both dirs)
                float x = apts[c*3+0], y = apts[c*3+1], zc = apts[c*3+2];
                af[t][0] = bf16s(x); af[t][1] = bf16s(y); af[t][2] = bf16s(zc);
                af[t][3] = (short)0x3F80;  // 1.0 bf16
                saux[w * 128 + t * 16 + l15] = x*x + y*y + zc*zc;
            }
        }
        __syncthreads();

        const float4_t* bp = (const float4_t*)saux;
        float4_t bias[8], c[8];
        #pragma unroll
        for (int t = 0; t < 8; ++t) {
            bias[t] = bp[w * 32 + t * 4 + quad];
            c[t] = (float4_t){BIGF, BIGF, BIGF, BIGF};
        }

        const uint4* bptr = spts + l15;   // quads duplicate address = broadcast
        #pragma unroll 2
        for (int ip = 0; ip < 16; ++ip) {             // 2 col-tiles per iter
            short8_t bf0 = __builtin_bit_cast(short8_t, bptr[(2*ip+0) * 16]);
            short8_t bf1 = __builtin_bit_cast(short8_t, bptr[(2*ip+1) * 16]);
            float4_t d0[8], d1[8];
            #pragma unroll
            for (int t = 0; t < 8; ++t)
                d0[t] = __builtin_amdgcn_mfma_f32_16x16x32_bf16(af[t], bf0, bias[t], 0, 0, 0);
            #pragma unroll
            for (int t = 0; t < 8; ++t)
                d1[t] = __builtin_amdgcn_mfma_f32_16x16x32_bf16(af[t], bf1, bias[t], 0, 0, 0);
            float cA0 = BIGF, cB0 = BIGF, cA1 = BIGF, cB1 = BIGF;
            #pragma unroll
            for (int t = 0; t < 8; ++t) {
                // row accumulate: one min3 per reg per 2 tiles
                c[t].x = min3f(c[t].x, d0[t].x, d1[t].x);
                c[t].y = min3f(c[t].y, d0[t].y, d1[t].y);
                c[t].z = min3f(c[t].z, d0[t].z, d1[t].z);
                c[t].w = min3f(c[t].w, d0[t].w, d1[t].w);
                // col collapse: per-lane min over this tile's 4 rows
                float m0 = min3f(d0[t].x, d0[t].y, d0[t].z);
                float m1 = min3f(d1[t].x, d1[t].y, d1[t].z);
                if (t & 1) { cB0 = min3f(cB0, m0, d0[t].w); cB1 = min3f(cB1, m1, d1[t].w); }
                else       { cA0 = min3f(cA0, m0, d0[t].w); cA1 = min3f(cA1, m1, d1[t].w); }
            }
            // cross-quad reduce in-register, per-wave global store (no LDS)
            float cm0 = fminf(cA0, cB0);
            float cm1 = fminf(cA1, cB1);
            cm0 = fminf(cm0, __shfl_xor(cm0, 16, 64));
            cm0 = fminf(cm0, __shfl_xor(cm0, 32, 64));
            cm1 = fminf(cm1, __shfl_xor(cm1, 16, 64));
            cm1 = fminf(cm1, __shfl_xor(cm1, 32, 64));
            if (quad == 0) {
                dstCW[(2*ip+0)*16 + l15] = fmaxf(cm0, 0.f);
                dstCW[(2*ip+1)*16 + l15] = fmaxf(cm1, 0.f);
            }
        }

        // ---- row (p2gt) epilogue: reduce across cols, PLAIN float4 store ----
        #pragma unroll
        for (int t = 0; t < 8; ++t) {
            quad_min4(c[t]);
            if (l15 == 0) {
                int m0 = abase + w * 128 + t * 16 + quad * 4;
                if (m0 < M_) {   // M_ % 4 == 0 -> no straddle
                    float4_t v;
                    v.x = fmaxf(c[t].x, 0.f); v.y = fmaxf(c[t].y, 0.f);
                    v.z = fmaxf(c[t].z, 0.f); v.w = fmaxf(c[t].w, 0.f);
                    *(float4_t*)(dstR + m0) = v;
                }
            }
        }
    } else {
        // ------------- fff role (single pass, per-block partial slots) -------
        const int kb = bid - NB_CH;
        const int i  = kb * 256 + tid;
        volatile float* red4 = saux + 512;
        float* slot = ws + WS_SLOT + (size_t)kb * 18;
        float* sA = saux;   // [0..7]
        if (tid < B_) sA[tid] = 0.f;
        __syncthreads();

        float vE=0.f,vG=0.f,vMC=0.f,vST=0.f,vF2=0.f,vE2=0.f,vEI=0.f,
              vG2=0.f,vGI=0.f,vI=0.f;
        if (i < B_ * M_) {
            const int b = i / M_;
            const int m = i - b * M_;
            const float* f = fff + (size_t)i * 3;
            float E = f[0], F = f[1], G = f[2];
            float A2  = fmaxf(E * G - F * F, 0.f);
            float inv = 1.f / (A2 + EPS_);
            vE = E; vG = G;
            vST = (E - G) * (E - G) * inv;
            vF2 = F * F * inv;
            vE2 = E * E * inv; vEI = E * inv;
            vG2 = G * G * inv; vGI = G * inv;
            vI  = inv;
            atomicAdd(&sA[b], sqrtf(A2));   // LDS atomic (cheap)
            if ((b & 1) == 0) {
                const float* f2 = fff + ((size_t)(b + 1) * M_ + m) * 3;
                float dE = E - f2[0], dF = F - f2[1], dG = G - f2[2];
                vMC = dE * dE + 2.f * dF * dF + dG * dG;
            }
        }
        float r;
        r = block_sum256(vE,  red4); if (tid==0) slot[A_E]   = r;
        r = block_sum256(vG,  red4); if (tid==0) slot[A_G]   = r;
        r = block_sum256(vMC, red4); if (tid==0) slot[A_MC]  = r;
        r = block_sum256(vST, red4); if (tid==0) slot[A_ST]  = r;
        r = block_sum256(vF2, red4); if (tid==0) slot[A_F2I] = r;
        r = block_sum256(vE2, red4); if (tid==0) slot[A_E2I] = r;
        r = block_sum256(vEI, red4); if (tid==0) slot[A_EI]  = r;
        r = block_sum256(vG2, red4); if (tid==0) slot[A_G2I] = r;
        r = block_sum256(vGI, red4); if (tid==0) slot[A_GI]  = r;
        r = block_sum256(vI,  red4); if (tid==0) slot[A_I]   = r;
        __syncthreads();
        if (tid < B_) slot[A_AB + tid] = sA[tid];   // unconditional: no init needed
    }
}

// ============================================================================
// Kernel 2: min-combine partials (float4) + sum; last block finalizes.
// gt2p: min over 20 (5 mblk x 4 waves); p2gt: min over 16 z.
// ============================================================================
__global__ void __launch_bounds__(256) k2_reduce(
        const float* __restrict__ A_gt, float* __restrict__ ws,
        float* __restrict__ out) {
    __shared__ float red4[4];
    __shared__ unsigned old_s;
    const int bid = blockIdx.x;
    const int tid = threadIdx.x;
    float* redp = ws + WS_RED;

    if (bid < NB_SG) {
        // gt2p: 16384 float4 outputs, min over 20 (m,w) partials
        const float4_t* g4 = (const float4_t*)(ws + WS_G2P);
        const int o4 = bid * 256 + tid;              // [0,16384)
        float4_t v = g4[o4];
        #pragma unroll
        for (int mw = 1; mw < 20; ++mw) min4v(v, g4[(size_t)mw * 16384 + o4]);
        float s = (v.x + v.y) + (v.z + v.w);
        float r = block_sum256(s, red4);
        if (tid == 0) redp[bid] = r;
    } else {
        // p2gt: 5000 float4 outputs, min over 16 z partials
        const int kb = bid - NB_SG;
        const float4_t* p4 = (const float4_t*)(ws + WS_P2P);
        const int o4 = kb * 256 + tid;               // [0,5120)
        float s = 0.f;
        if (o4 < 5000) {
            float4_t v = p4[o4];
            #pragma unroll
            for (int z = 1; z < 16; ++z) min4v(v, p4[(size_t)z * 5000 + o4]);
            s = (v.x + v.y) + (v.z + v.w);
        }
        float r = block_sum256(s, red4);
        if (tid == 0) redp[NB_SG + kb] = r;
    }

    // ---- arrival counter; last block finalizes ----
    __syncthreads();
    if (tid == 0) __threadfence();
    __syncthreads();
    if (tid == 0)
        old_s = __hip_atomic_fetch_add((unsigned*)(ws + WS_CNT), 1u,
                                       __ATOMIC_ACQ_REL, __HIP_MEMORY_SCOPE_AGENT);
    __syncthreads();
    if (old_s != (unsigned)(NB_K2 - 1)) return;

    float sG = block_sum256((tid < NB_SG) ? redp[tid] : 0.f, red4);
    float sP = block_sum256((tid < NB_SP) ? redp[NB_SG + tid] : 0.f, red4);

    float a[18];
    #pragma unroll
    for (int k = 0; k < 18; ++k) {
        float t = (tid < NB_FFF) ? ws[WS_SLOT + (size_t)tid * 18 + k] : 0.f;
        a[k] = block_sum256(t, red4);
    }

    if (tid == 0) {
        const float inv20k = 1.f / 20000.f;
        float mE = a[A_E] * inv20k, mG = a[A_G] * inv20k;
        float L_E = (a[A_E2I] - 2.f*mE*a[A_EI] + mE*mE*a[A_I]) * inv20k;
        float L_G = (a[A_G2I] - 2.f*mG*a[A_GI] + mG*mG*a[A_I]) * inv20k;
        float L_sc = L_E + L_G + (a[A_ST] + a[A_F2I]) * inv20k;
        float L_mc = a[A_MC] * (1.f / 10000.f);
        float L_chd = sP * inv20k + sG * (1.f / 65536.f);
        float L_olap = 0.f;
        #pragma unroll
        for (int b = 0; b < B_; ++b) {
            float At = a[A_AB + b] * (1.f / (float)SPP_);
            float d  = fmaxf(0.f, At - A_gt[b]);
            L_olap += d * d;
        }
        L_olap *= (1.f / (float)B_);
        out[0] = L_chd + L_mc + L_sc + L_olap;
    }
}

extern "C" void kernel_launch(void* const* d_in, const int* in_sizes, int n_in,
                              void* d_out, int out_size, void* d_ws, size_t ws_size,
                              hipStream_t stream) {
    const float* pc_gt   = (const float*)d_in[0];   // (8, 8192, 3)
    const float* pc_pred = (const float*)d_in[1];   // (8, 2500, 3)
    const float* fff     = (const float*)d_in[2];   // (8, 2500, 3)
    const float* A_gt    = (const float*)d_in[3];   // (8,)
    float* ws  = (float*)d_ws;                      // ~6.5 MB used
    float* out = (float*)d_out;

    // NO memsets: every ws cell consumed is plain-stored first (partials,
    // slots, redp) or zeroed by k1 block 0 (k2's arrival counter).
    k1_main  <<<NB_K1, 256, 0, stream>>>(pc_gt, pc_pred, fff, ws);
    k2_reduce<<<NB_K2, 256, 0, stream>>>(A_gt, ws, out);
}

// Round 6
// 91.326 us; speedup vs baseline: 1.0905x; 1.0905x over previous
//
#include <hip/hip_runtime.h>

// Problem constants (from reference: B=8, N=8192, M=2500, P=10)
#define B_   8
#define N_   8192
#define M_   2500
#define SPP_ 250
#define EPS_ 1e-20f
#define BIGF 1e30f

// ---- kernel-1 roles ----
// unified chamfer: 16 gtblk (512 gt) x 8 b x 5 mblk (512 preds) = 640 blocks.
// Each block computes its 512x512 distance tile ONCE and PLAIN-STORES its
// owned slice of row-min partials [z][b][2500] and col-min partials
// [m][b][8192]. No device atomics, no fences, no init needed.
// LDS ~18.6 KB (scol collapsed per-wave via in-register cross-quad shfl)
// -> residency 4 blocks/CU (VGPR-bound), whole 719-block grid co-resident.
#define NB_CH   640
#define NB_FFF  79
#define NB_K1   (NB_CH + NB_FFF)   // 719

// ---- kernel-2: min-combine partials + finalize ----
#define NB_SG   64                 // 65536 gt2p outputs (min over 5)
#define NB_SP   20                 // 20000 p2gt outputs (min over 16)
#define NB_K2   (NB_SG + NB_SP)    // 84

// ---- ws layout (float indices); everything plain-stored before read ----
#define WS_P2P  0                  // [16 z][8 b][2500] row-min partials
#define WS_G2P  320000             // [5 m][8 b][8192] col-min partials
#define WS_SLOT 647680             // [79][18] fff per-block partials
#define WS_RED  649102             // [84] k2 per-block partial sums
#define WS_CNT  649186             // k2 arrival counter (zeroed by k1 blk 0)
// slot indices
#define A_E    0
#define A_G    1
#define A_MC   2
#define A_ST   3
#define A_F2I  4
#define A_E2I  5
#define A_EI   6
#define A_G2I  7
#define A_GI   8
#define A_I    9
#define A_AB   10   // 10..17 per-batch sum sqrt(A2)

typedef __attribute__((ext_vector_type(8))) short short8_t;
typedef __attribute__((ext_vector_type(4))) float float4_t;

__device__ __forceinline__ unsigned pack_bf2(float lo, float hi) {
    unsigned a = __float_as_uint(lo);
    unsigned b = __float_as_uint(hi);
    a = (a + 0x7FFFu + ((a >> 16) & 1u)) >> 16;
    b = (b + 0x7FFFu + ((b >> 16) & 1u)) & 0xFFFF0000u;
    return a | b;
}
__device__ __forceinline__ short bf16s(float x) {
    unsigned a = __float_as_uint(x);
    return (short)((a + 0x7FFFu + ((a >> 16) & 1u)) >> 16);
}
// 3-input min, single VALU instr (values are never NaN here)
__device__ __forceinline__ float min3f(float a, float b, float c) {
    float r;
    asm("v_min3_f32 %0, %1, %2, %3" : "=v"(r) : "v"(a), "v"(b), "v"(c));
    return r;
}
__device__ __forceinline__ float wave_sum64(float v) {
    #pragma unroll
    for (int o = 32; o > 0; o >>= 1) v += __shfl_down(v, o, 64);
    return v;
}
__device__ __forceinline__ float block_sum256(float v, volatile float* red4) {
    v = wave_sum64(v);
    int wid = threadIdx.x >> 6, lane = threadIdx.x & 63;
    if (lane == 0) red4[wid] = v;
    __syncthreads();
    float r = 0.f;
    if (threadIdx.x == 0) r = red4[0] + red4[1] + red4[2] + red4[3];
    __syncthreads();
    return r;
}
__device__ __forceinline__ void quad_min4(float4_t& c) {
    #pragma unroll
    for (int m = 1; m < 16; m <<= 1) {
        c.x = fminf(c.x, __shfl_xor(c.x, m, 64));
        c.y = fminf(c.y, __shfl_xor(c.y, m, 64));
        c.z = fminf(c.z, __shfl_xor(c.z, m, 64));
        c.w = fminf(c.w, __shfl_xor(c.w, m, 64));
    }
}
__device__ __forceinline__ void min4v(float4_t& c, const float4_t d) {
    c.x = fminf(c.x, d.x); c.y = fminf(c.y, d.y);
    c.z = fminf(c.z, d.z); c.w = fminf(c.w, d.w);
}

// ============================================================================
// Kernel 1: MFMA chamfer (one distance-matrix pass, both directions) + fff.
// Pure compute + owned plain stores. No cross-block protocol of any kind.
// ============================================================================
__global__ void __launch_bounds__(256, 2) k1_main(
        const float* __restrict__ gt, const float* __restrict__ pred,
        const float* __restrict__ fff, float* __restrict__ ws) {
    __shared__ uint4 spts[512];                  // staged gt pts, 16 B each
    __shared__ __align__(16) float saux[516];    // 512 row norms + red4
    __shared__ float scol[4][520];               // per-WAVE col minima (pad 8)
    const int bid = blockIdx.x;
    const int tid = threadIdx.x;
    const int lane = tid & 63;
    const int w    = tid >> 6;
    const int quad = lane >> 4;
    const int l15  = lane & 15;

    if (bid == 0 && tid == 0)
        ((unsigned*)(ws + WS_CNT))[0] = 0u;      // k2 counter (kernel-boundary ordered)

    if (bid < NB_CH) {
        // ------------------- unified chamfer role -------------------
        const int z = bid / 40;         // gt chunk (512 pts), 16 chunks
        const int rem = bid % 40;
        const int b = rem / 5;
        const int mblk = rem % 5;       // pred chunk (512 rows)
        const float* apts = pred + (size_t)b * M_ * 3;
        const float* bpts = gt + ((size_t)b * N_ + (size_t)z * 512) * 3;
        const int abase = mblk * 512;
        float* dstR = ws + WS_P2P + (size_t)z * 20000 + b * M_;          // owned rows
        float* dstC = ws + WS_G2P + (size_t)mblk * 65536 + b * N_ + z * 512; // owned cols

        // A fragments FIRST (scattered loads issue early, overlap staging):
        // 8 tiles of 16 rows per wave (128 rows); stash norms in saux.
        short8_t af[8];
        #pragma unroll
        for (int t = 0; t < 8; ++t) af[t] = (short8_t){0,0,0,0,0,0,0,0};
        if (lane < 16) {
            #pragma unroll
            for (int t = 0; t < 8; ++t) {
                int m = abase + w * 128 + t * 16 + l15;
                int c = m < M_ ? m : M_ - 1;   // dup row 2499 (harmless both dirs)
                float x = apts[c*3+0], y = apts[c*3+1], zc = apts[c*3+2];
                af[t][0] = bf16s(x); af[t][1] = bf16s(y); af[t][2] = bf16s(zc);
                af[t][3] = (short)0x3F80;  // 1.0 bf16
                saux[w * 128 + t * 16 + l15] = x*x + y*y + zc*zc;
            }
        }

        // stage gt points (bf16, -2 folded, norm in w; halves duplicated)
        for (int i = tid; i < 512; i += 256) {
            const float* q3 = bpts + i * 3;
            float x = q3[0], y = q3[1], zc = q3[2];
            float n2 = x * x + y * y + zc * zc;
            uint4 q;
            q.x = pack_bf2(-2.f * x, -2.f * y);
            q.y = pack_bf2(-2.f * zc, n2);
            q.z = q.x; q.w = q.y;
            spts[i] = q;
        }
        __syncthreads();

        const float4_t* bp = (const float4_t*)saux;
        float4_t bias[8], c[8];
        #pragma unroll
        for (int t = 0; t < 8; ++t) {
            bias[t] = bp[w * 32 + t * 4 + quad];
            c[t] = (float4_t){BIGF, BIGF, BIGF, BIGF};
        }

        const uint4* bptr = spts + l15;   // quads duplicate address = broadcast
        #pragma unroll 2
        for (int ip = 0; ip < 16; ++ip) {             // 2 col-tiles per iter
            short8_t bf0 = __builtin_bit_cast(short8_t, bptr[(2*ip+0) * 16]);
            short8_t bf1 = __builtin_bit_cast(short8_t, bptr[(2*ip+1) * 16]);
            float4_t d0[8], d1[8];
            #pragma unroll
            for (int t = 0; t < 8; ++t)
                d0[t] = __builtin_amdgcn_mfma_f32_16x16x32_bf16(af[t], bf0, bias[t], 0, 0, 0);
            #pragma unroll
            for (int t = 0; t < 8; ++t)
                d1[t] = __builtin_amdgcn_mfma_f32_16x16x32_bf16(af[t], bf1, bias[t], 0, 0, 0);
            float cA0 = BIGF, cB0 = BIGF, cA1 = BIGF, cB1 = BIGF;
            #pragma unroll
            for (int t = 0; t < 8; ++t) {
                // row accumulate: one min3 per reg per 2 tiles
                c[t].x = min3f(c[t].x, d0[t].x, d1[t].x);
                c[t].y = min3f(c[t].y, d0[t].y, d1[t].y);
                c[t].z = min3f(c[t].z, d0[t].z, d1[t].z);
                c[t].w = min3f(c[t].w, d0[t].w, d1[t].w);
                // col collapse: per-lane min over this tile's 4 rows
                float m0 = min3f(d0[t].x, d0[t].y, d0[t].z);
                float m1 = min3f(d1[t].x, d1[t].y, d1[t].z);
                if (t & 1) { cB0 = min3f(cB0, m0, d0[t].w); cB1 = min3f(cB1, m1, d1[t].w); }
                else       { cA0 = min3f(cA0, m0, d0[t].w); cA1 = min3f(cA1, m1, d1[t].w); }
            }
            // cross-quad reduce in-register (exact min, order-free), then one
            // 16-lane LDS write per col-tile -> scol is per-wave, 8.3 KB total
            float cm0 = fminf(cA0, cB0);
            float cm1 = fminf(cA1, cB1);
            cm0 = fminf(cm0, __shfl_xor(cm0, 16, 64));
            cm0 = fminf(cm0, __shfl_xor(cm0, 32, 64));
            cm1 = fminf(cm1, __shfl_xor(cm1, 16, 64));
            cm1 = fminf(cm1, __shfl_xor(cm1, 32, 64));
            if (lane < 16) {
                scol[w][(2*ip+0)*16 + l15] = cm0;
                scol[w][(2*ip+1)*16 + l15] = cm1;
            }
        }

        // ---- row (p2gt) epilogue: reduce across cols, PLAIN float4 store ----
        #pragma unroll
        for (int t = 0; t < 8; ++t) {
            quad_min4(c[t]);
            if (l15 == 0) {
                int m0 = abase + w * 128 + t * 16 + quad * 4;
                if (m0 < M_) {   // M_ % 4 == 0 -> no straddle
                    float4_t v;
                    v.x = fmaxf(c[t].x, 0.f); v.y = fmaxf(c[t].y, 0.f);
                    v.z = fmaxf(c[t].z, 0.f); v.w = fmaxf(c[t].w, 0.f);
                    *(float4_t*)(dstR + m0) = v;
                }
            }
        }

        // ---- col (gt2p) epilogue: combine the 4 waves, PLAIN store ----
        __syncthreads();
        #pragma unroll
        for (int rr = 0; rr < 2; ++rr) {
            int j = rr * 256 + tid;
            float v = fminf(fminf(scol[0][j], scol[1][j]),
                            fminf(scol[2][j], scol[3][j]));
            dstC[j] = fmaxf(v, 0.f);
        }
    } else {
        // ------------- fff role (single pass, per-block partial slots) -------
        const int kb = bid - NB_CH;
        const int i  = kb * 256 + tid;
        volatile float* red4 = saux + 512;
        float* slot = ws + WS_SLOT + (size_t)kb * 18;
        float* sA = saux;   // [0..7]
        if (tid < B_) sA[tid] = 0.f;
        __syncthreads();

        float vE=0.f,vG=0.f,vMC=0.f,vST=0.f,vF2=0.f,vE2=0.f,vEI=0.f,
              vG2=0.f,vGI=0.f,vI=0.f;
        if (i < B_ * M_) {
            const int b = i / M_;
            const int m = i - b * M_;
            const float* f = fff + (size_t)i * 3;
            float E = f[0], F = f[1], G = f[2];
            float A2  = fmaxf(E * G - F * F, 0.f);
            float inv = 1.f / (A2 + EPS_);
            vE = E; vG = G;
            vST = (E - G) * (E - G) * inv;
            vF2 = F * F * inv;
            vE2 = E * E * inv; vEI = E * inv;
            vG2 = G * G * inv; vGI = G * inv;
            vI  = inv;
            atomicAdd(&sA[b], sqrtf(A2));   // LDS atomic (cheap)
            if ((b & 1) == 0) {
                const float* f2 = fff + ((size_t)(b + 1) * M_ + m) * 3;
                float dE = E - f2[0], dF = F - f2[1], dG = G - f2[2];
                vMC = dE * dE + 2.f * dF * dF + dG * dG;
            }
        }
        float r;
        r = block_sum256(vE,  red4); if (tid==0) slot[A_E]   = r;
        r = block_sum256(vG,  red4); if (tid==0) slot[A_G]   = r;
        r = block_sum256(vMC, red4); if (tid==0) slot[A_MC]  = r;
        r = block_sum256(vST, red4); if (tid==0) slot[A_ST]  = r;
        r = block_sum256(vF2, red4); if (tid==0) slot[A_F2I] = r;
        r = block_sum256(vE2, red4); if (tid==0) slot[A_E2I] = r;
        r = block_sum256(vEI, red4); if (tid==0) slot[A_EI]  = r;
        r = block_sum256(vG2, red4); if (tid==0) slot[A_G2I] = r;
        r = block_sum256(vGI, red4); if (tid==0) slot[A_GI]  = r;
        r = block_sum256(vI,  red4); if (tid==0) slot[A_I]   = r;
        __syncthreads();
        if (tid < B_) slot[A_AB + tid] = sA[tid];   // unconditional: no init needed
    }
}

// ============================================================================
// Kernel 2: min-combine partials (float4) + sum; last block finalizes.
// Only these 84 blocks run the fence+counter protocol.
// ============================================================================
__global__ void __launch_bounds__(256) k2_reduce(
        const float* __restrict__ A_gt, float* __restrict__ ws,
        float* __restrict__ out) {
    __shared__ float red4[4];
    __shared__ unsigned old_s;
    const int bid = blockIdx.x;
    const int tid = threadIdx.x;
    float* redp = ws + WS_RED;

    if (bid < NB_SG) {
        // gt2p: 16384 float4 outputs, min over 5 mblk partials
        const float4_t* g4 = (const float4_t*)(ws + WS_G2P);
        const int o4 = bid * 256 + tid;              // [0,16384)
        float4_t v = g4[o4];
        #pragma unroll
        for (int m = 1; m < 5; ++m) min4v(v, g4[(size_t)m * 16384 + o4]);
        float s = (v.x + v.y) + (v.z + v.w);
        float r = block_sum256(s, red4);
        if (tid == 0) redp[bid] = r;
    } else {
        // p2gt: 5000 float4 outputs, min over 16 z partials
        const int kb = bid - NB_SG;
        const float4_t* p4 = (const float4_t*)(ws + WS_P2P);
        const int o4 = kb * 256 + tid;               // [0,5120)
        float s = 0.f;
        if (o4 < 5000) {
            float4_t v = p4[o4];
            #pragma unroll
            for (int z = 1; z < 16; ++z) min4v(v, p4[(size_t)z * 5000 + o4]);
            s = (v.x + v.y) + (v.z + v.w);
        }
        float r = block_sum256(s, red4);
        if (tid == 0) redp[NB_SG + kb] = r;
    }

    // ---- arrival counter; last block finalizes ----
    __syncthreads();
    if (tid == 0) __threadfence();
    __syncthreads();
    if (tid == 0)
        old_s = __hip_atomic_fetch_add((unsigned*)(ws + WS_CNT), 1u,
                                       __ATOMIC_ACQ_REL, __HIP_MEMORY_SCOPE_AGENT);
    __syncthreads();
    if (old_s != (unsigned)(NB_K2 - 1)) return;

    float sG = block_sum256((tid < NB_SG) ? redp[tid] : 0.f, red4);
    float sP = block_sum256((tid < NB_SP) ? redp[NB_SG + tid] : 0.f, red4);

    float a[18];
    #pragma unroll
    for (int k = 0; k < 18; ++k) {
        float t = (tid < NB_FFF) ? ws[WS_SLOT + (size_t)tid * 18 + k] : 0.f;
        a[k] = block_sum256(t, red4);
    }

    if (tid == 0) {
        const float inv20k = 1.f / 20000.f;
        float mE = a[A_E] * inv20k, mG = a[A_G] * inv20k;
        float L_E = (a[A_E2I] - 2.f*mE*a[A_EI] + mE*mE*a[A_I]) * inv20k;
        float L_G = (a[A_G2I] - 2.f*mG*a[A_GI] + mG*mG*a[A_I]) * inv20k;
        float L_sc = L_E + L_G + (a[A_ST] + a[A_F2I]) * inv20k;
        float L_mc = a[A_MC] * (1.f / 10000.f);
        float L_chd = sP * inv20k + sG * (1.f / 65536.f);
        float L_olap = 0.f;
        #pragma unroll
        for (int b = 0; b < B_; ++b) {
            float At = a[A_AB + b] * (1.f / (float)SPP_);
            float d  = fmaxf(0.f, At - A_gt[b]);
            L_olap += d * d;
        }
        L_olap *= (1.f / (float)B_);
        out[0] = L_chd + L_mc + L_sc + L_olap;
    }
}

extern "C" void kernel_launch(void* const* d_in, const int* in_sizes, int n_in,
                              void* d_out, int out_size, void* d_ws, size_t ws_size,
                              hipStream_t stream) {
    const float* pc_gt   = (const float*)d_in[0];   // (8, 8192, 3)
    const float* pc_pred = (const float*)d_in[1];   // (8, 2500, 3)
    const float* fff     = (const float*)d_in[2];   // (8, 2500, 3)
    const float* A_gt    = (const float*)d_in[3];   // (8,)
    float* ws  = (float*)d_ws;                      // ~2.6 MB used
    float* out = (float*)d_out;

    // NO memsets: every ws cell consumed is plain-stored first (partials,
    // slots, redp) or zeroed by k1 block 0 (k2's arrival counter).
    k1_main  <<<NB_K1, 256, 0, stream>>>(pc_gt, pc_pred, fff, ws);
    k2_reduce<<<NB_K2, 256, 0, stream>>>(A_gt, ws, out);
}